// Round 4
// baseline (303.604 us; speedup 1.0000x reference)
//
#include <hip/hip_runtime.h>
#include <hip/hip_bf16.h>
#include <math.h>

typedef float floatx4 __attribute__((ext_vector_type(4)));

#define IN_DIM 128
#define OUT_DIM 64
// XCD-ownership of node d: 16 consecutive nodes share one owner in 0..7;
// blockIdx%8 round-robins XCDs so all RMWs/stores for a cursor/ssort line
// come from one XCD -> no cross-XCD line migration. (proven R9/R10)
#define OWNER(d) (((d) >> 4) & 7)
#define CHUNK 2048
#define CAP 32        // 128 B = 2 lines per node; P(Poisson(16)>32) ~ 2e-4
#define OVF_CAP 8192  // exact overflow path

// ---------------------------------------------------------------------------
// VALU GEMM: z = h @ W^T (fp32 exact), bf16 z out, fp32 s_src/s_dst out.
// K-split staging: two halves of 16 k4 reuse one 24.75 KB LDS footprint
// (was 50 KB -> 3 blocks/CU -> 3 waves/SIMD; ds_read->FMA latency exposed).
// Now 6 blocks/CU. NO min-waves launch bound: R2 showed forcing it spills
// the acc[8] accumulators to scratch (VGPR pinned to 40 -> 6 GB scratch).
// FMA order per accumulator unchanged -> bit-identical results.
// ---------------------------------------------------------------------------
__global__ __launch_bounds__(256) void k_gemm(
    const float* __restrict__ h, const float* __restrict__ W,
    const float* __restrict__ a, __hip_bfloat16* __restrict__ z,
    float* __restrict__ s_src, float* __restrict__ s_dst, int N)
{
    __shared__ floatx4 sW[16 * 65];   // [k4l][c], pad 65 -> 16.25 KB
    __shared__ floatx4 sH[32 * 17];   // [n][k4l], pad 17 ->  8.5 KB

    const int tid = threadIdx.x;
    const int n0 = blockIdx.x * 32;
    const int wave = tid >> 6;
    const int c = tid & 63;

    floatx4 acc[8];
#pragma unroll
    for (int i = 0; i < 8; ++i) acc[i] = (floatx4){0.f, 0.f, 0.f, 0.f};

    const floatx4* W4 = (const floatx4*)W;
    const floatx4* H4 = (const floatx4*)h;

    for (int kh = 0; kh < 2; ++kh) {
        if (kh) __syncthreads();          // LDS reuse between halves
#pragma unroll
        for (int i = 0; i < 4; ++i) {
            int gg = tid + 256 * i;       // 0..1023
            int cc = gg >> 4, k4l = gg & 15;
            sW[k4l * 65 + cc] = W4[cc * 32 + kh * 16 + k4l];
        }
#pragma unroll
        for (int i = 0; i < 2; ++i) {
            int gg = tid + 256 * i;       // 0..511
            int n = gg >> 4, k4l = gg & 15;
            sH[n * 17 + k4l] = H4[(size_t)(n0 + n) * 32 + kh * 16 + k4l];
        }
        __syncthreads();

        for (int k4l = 0; k4l < 16; ++k4l) {
            floatx4 w4 = sW[k4l * 65 + c];
#pragma unroll
            for (int i = 0; i < 8; ++i) {
                floatx4 h4 = sH[(wave * 8 + i) * 17 + k4l];  // broadcast
                acc[i].x += h4.x * w4.x;
                acc[i].y += h4.y * w4.y;
                acc[i].z += h4.z * w4.z;
                acc[i].w += h4.w * w4.w;
            }
        }
    }

    const float a1 = a[c];
    const float a2 = a[OUT_DIM + c];
#pragma unroll
    for (int i = 0; i < 8; ++i) {
        int n = n0 + wave * 8 + i;
        float v = (acc[i].x + acc[i].y) + (acc[i].z + acc[i].w);
        z[(size_t)n * OUT_DIM + c] = __float2bfloat16(v);
        float ps = v * a1;
        float pd = v * a2;
#pragma unroll
        for (int off = 32; off >= 1; off >>= 1) {
            ps += __shfl_xor(ps, off);
            pd += __shfl_xor(pd, off);
        }
        if (c == 0) {
            s_src[n] = ps;
            s_dst[n] = pd;
        }
    }
}

// ---------------------------------------------------------------------------
// Direct slotted scatter — byte-identical to the 285 us baseline (82 us).
// R3 post-mortem: MLP-batching the 8 iterations REGRESSED to 94 us (burst
// same-line atomic contention + predication VALU); keep the simple form.
// nt loads on src/dst: each line read once per XCD, keeps the streaming
// reads from evicting partially-filled ssort lines.
// ---------------------------------------------------------------------------
__global__ __launch_bounds__(256) void k_scatter(
    const int* __restrict__ src, const int* __restrict__ dst,
    int* __restrict__ cursor, int* __restrict__ ssort,
    int* __restrict__ ovfcnt, int2* __restrict__ ovf, int E)
{
    const int x = blockIdx.x & 7;
    const int c = blockIdx.x >> 3;
    const int e0 = c * CHUNK;
#pragma unroll
    for (int i = 0; i < CHUNK / 256; ++i) {
        int e = e0 + i * 256 + threadIdx.x;
        if (e < E) {
            int d = __builtin_nontemporal_load(&dst[e]);
            if (OWNER(d) == x) {
                int s = __builtin_nontemporal_load(&src[e]);
                int pos = atomicAdd(&cursor[d], 1);
                if (pos < CAP) {
                    ssort[d * CAP + pos] = s;
                } else {
                    int op = atomicAdd(ovfcnt, 1);
                    if (op < OVF_CAP) ovf[op] = make_int2(s, d);
                }
            }
        }
    }
}

// ---------------------------------------------------------------------------
// Fused per-node softmax + weighted gather + ELU. One wave/node, lane=col.
// Unshifted exp (validated R9/R10). 8-wide predicated gather unroll.
// nt on single-use streams (ssort read, out write) to keep z in L2.
// ---------------------------------------------------------------------------
__global__ __launch_bounds__(256) void k_node(
    const int* __restrict__ cursor, const int* __restrict__ ssort,
    const float* __restrict__ s_src, const float* __restrict__ s_dst,
    const int* __restrict__ ovfcnt, const int2* __restrict__ ovf,
    const __hip_bfloat16* __restrict__ z, float* __restrict__ out, int N)
{
    const int lane = threadIdx.x & 63;
    const int wave = threadIdx.x >> 6;
    const int n = blockIdx.x * 4 + wave;
    if (n >= N) return;

    const int deg_raw = cursor[n];
    if (deg_raw == 0) {                   // empty segment -> elu(0) = 0
        __builtin_nontemporal_store(0.f, &out[(size_t)n * OUT_DIM + lane]);
        return;
    }
    const int deg = min(deg_raw, CAP);
    const int base = n * CAP;
    const float sdn = s_dst[n];

    float sum = 0.f;                      // lane-partial softmax denom
    float acc = 0.f;                      // weighted feature accumulator
    {
        int kk = lane;                    // deg <= CAP=32 < 64: single pass
        int sv = 0;
        float ev = 0.f;
        if (kk < deg) {
            sv = __builtin_nontemporal_load(&ssort[base + kk]);
            float sc = s_src[sv] + sdn;
            sc = sc > 0.f ? sc : 0.01f * sc;   // leaky_relu
            ev = __expf(sc);
        }
        sum += ev;
        for (int j = 0; j < deg; j += 8) {
            float wgt[8], zv[8];
#pragma unroll
            for (int u = 0; u < 8; ++u) {
                int jj = j + u;
                bool ok = jj < deg;
                int s = __shfl(sv, ok ? jj : 0);
                float w = __shfl(ev, ok ? jj : 0);
                wgt[u] = ok ? w : 0.f;
                int sa = ok ? s : 0;
                zv[u] = __bfloat162float(z[(size_t)sa * OUT_DIM + lane]);
            }
#pragma unroll
            for (int u = 0; u < 8; ++u) acc += wgt[u] * zv[u];
        }
    }

    // exact overflow path (deg_raw > CAP): ~20 nodes, ovf list tiny
    if (deg_raw > CAP) {
        int oc = min(*ovfcnt, OVF_CAP);
        for (int i = 0; i < oc; ++i) {
            int2 p = ovf[i];
            if (p.y == n) {
                float sc = s_src[p.x] + sdn;
                sc = sc > 0.f ? sc : 0.01f * sc;
                float ev = __expf(sc);
                if (lane == 0) sum += ev;
                acc += ev * __bfloat162float(z[(size_t)p.x * OUT_DIM + lane]);
            }
        }
    }

#pragma unroll
    for (int off = 32; off >= 1; off >>= 1) sum += __shfl_xor(sum, off);

    float r = acc / sum;
    float o = r > 0.f ? r : expm1f(r);    // ELU, alpha=1
    __builtin_nontemporal_store(o, &out[(size_t)n * OUT_DIM + lane]);
}

// ---------------------------------------------------------------------------
extern "C" void kernel_launch(void* const* d_in, const int* in_sizes, int n_in,
                              void* d_out, int out_size, void* d_ws, size_t ws_size,
                              hipStream_t stream)
{
    (void)n_in; (void)out_size; (void)ws_size;

    const float* h  = (const float*)d_in[0];
    const int* src  = (const int*)d_in[1];
    const int* dst  = (const int*)d_in[2];
    const float* W  = (const float*)d_in[3];
    const float* a  = (const float*)d_in[4];
    const int N = in_sizes[0] / IN_DIM;
    const int E = in_sizes[1];
    float* out = (float*)d_out;

    char* wsp = (char*)d_ws;
    size_t off = 0;
    auto alloc = [&](size_t bytes) -> void* {
        void* p = wsp + off;
        off = (off + bytes + 255) & ~(size_t)255;
        return p;
    };
    __hip_bfloat16* z = (__hip_bfloat16*)alloc((size_t)N * OUT_DIM * 2);
    float* s_src = (float*)alloc((size_t)N * 4);
    float* s_dst = (float*)alloc((size_t)N * 4);
    int* cursor  = (int*)alloc((size_t)(N + 1) * 4);   // +1: ovfcnt tail
    int* ovfcnt  = cursor + N;
    int2* ovf    = (int2*)alloc((size_t)OVF_CAP * 8);
    int* ssort   = (int*)alloc((size_t)N * CAP * 4);   // 12.8 MB
    // total ~27 MB for N=1e5

    hipMemsetAsync(cursor, 0, (size_t)(N + 1) * 4, stream);

    const int nchunks = (E + CHUNK - 1) / CHUNK;
    k_gemm<<<(N + 31) / 32, 256, 0, stream>>>(h, W, a, z, s_src, s_dst, N);
    k_scatter<<<nchunks * 8, 256, 0, stream>>>(src, dst, cursor, ssort, ovfcnt, ovf, E);
    k_node<<<(N + 3) / 4, 256, 0, stream>>>(cursor, ssort, s_src, s_dst, ovfcnt, ovf, z, out, N);
}

// Round 5
// 245.465 us; speedup vs baseline: 1.2369x; 1.2369x over previous
//
#include <hip/hip_runtime.h>
#include <hip/hip_bf16.h>
#include <math.h>

typedef float floatx4 __attribute__((ext_vector_type(4)));
typedef short short8 __attribute__((ext_vector_type(8)));

#define IN_DIM 128
#define OUT_DIM 64
// XCD-ownership of node d: 16 consecutive nodes share one owner in 0..7;
// blockIdx%8 round-robins XCDs so all RMWs/stores for a cursor/ssort line
// come from one XCD -> no cross-XCD line migration. (proven R9/R10)
#define OWNER(d) (((d) >> 4) & 7)
#define CHUNK 2048
#define CAP 32        // 128 B = 2 lines per node; P(Poisson(16)>32) ~ 2e-4
#define OVF_CAP 8192  // exact overflow path
#define WPAD 136      // ushort row stride for W in LDS (128 + 8 pad -> bank rotate)

__device__ __forceinline__ unsigned short bf16_rne(float f) {
    unsigned u = __float_as_uint(f);
    u += 0x7FFFu + ((u >> 16) & 1u);
    return (unsigned short)(u >> 16);
}
__device__ __forceinline__ float bf16_tof(unsigned short b) {
    return __uint_as_float(((unsigned)b) << 16);
}

// ---------------------------------------------------------------------------
// MFMA GEMM: z = h @ W^T via v_mfma_f32_16x16x32_bf16, SPLIT-PRECISION:
// h = h_hi + h_lo, W = W_hi + W_lo (bf16 RNE splits); z = hi*hi + lo*hi + hi*lo
// accumulated fp32 -> dropped lo*lo term ~2^-16 relative: z accuracy == fp32
// path, absmax unchanged. R4 post-mortem: VALU gemm is structurally 5-8x off
// its 10 us FMA floor (LDS-broadcast inner loop, latency-exposed); MFMA moves
// the dot products to the matrix pipe. Wave = 16 nodes x 64 cols, 48 MFMA.
// Fragment mapping (HW-verified m89/m91-93): A/B^T row = lane&15,
// k = 32*ks + 8*(lane>>4) + j; C/D col = lane&15, row = (lane>>4)*4 + reg.
// W staged once/block in LDS as bf16 hi/lo. A-frags direct from global
// (each 128-B h segment read exactly once, 4 lanes/row contiguous).
// ---------------------------------------------------------------------------
__global__ __launch_bounds__(256) void k_gemm(
    const float* __restrict__ h, const float* __restrict__ W,
    const float* __restrict__ a, __hip_bfloat16* __restrict__ z,
    float* __restrict__ s_src, float* __restrict__ s_dst, int N)
{
    __shared__ __align__(16) unsigned short sWhi[64 * WPAD];
    __shared__ __align__(16) unsigned short sWlo[64 * WPAD];

    const int tid = threadIdx.x;
    // stage W as bf16 hi/lo (one-time, coalesced fp32 read)
#pragma unroll
    for (int i = 0; i < 32; ++i) {
        int g = tid + 256 * i;            // 0..8191
        float f = W[g];
        int row = g >> 7, k = g & 127;
        unsigned short hb = bf16_rne(f);
        sWhi[row * WPAD + k] = hb;
        sWlo[row * WPAD + k] = bf16_rne(f - bf16_tof(hb));
    }

    const int wave = tid >> 6;
    const int l = tid & 63;
    const int lr = l & 15;                // A/B row-in-tile; C/D col
    const int lk = l >> 4;                // k-group / C/D row-group
    const int n0w = blockIdx.x * 64 + wave * 16;

    // A fragments: h rows n0w+lr, bf16 hi/lo split, 8 consecutive k per frag
    const int arow = min(n0w + lr, N - 1);   // clamp: garbage rows never stored
    const float* hrow = h + (size_t)arow * IN_DIM;
    short8 ahi[4], alo[4];
#pragma unroll
    for (int ks = 0; ks < 4; ++ks) {
        int k0 = 32 * ks + 8 * lk;
        floatx4 f0 = *(const floatx4*)(hrow + k0);
        floatx4 f1 = *(const floatx4*)(hrow + k0 + 4);
        float fv[8] = {f0.x, f0.y, f0.z, f0.w, f1.x, f1.y, f1.z, f1.w};
#pragma unroll
        for (int j = 0; j < 8; ++j) {
            unsigned short hb = bf16_rne(fv[j]);
            ahi[ks][j] = (short)hb;
            alo[ks][j] = (short)bf16_rne(fv[j] - bf16_tof(hb));
        }
    }
    __syncthreads();

    float ps[4] = {0.f, 0.f, 0.f, 0.f};
    float pd[4] = {0.f, 0.f, 0.f, 0.f};
#pragma unroll
    for (int ct = 0; ct < 4; ++ct) {
        floatx4 acc = (floatx4){0.f, 0.f, 0.f, 0.f};
#pragma unroll
        for (int ks = 0; ks < 4; ++ks) {
            const int boff = (ct * 16 + lr) * WPAD + 32 * ks + 8 * lk;
            short8 bhi = *(const short8*)&sWhi[boff];
            short8 blo = *(const short8*)&sWlo[boff];
            acc = __builtin_amdgcn_mfma_f32_16x16x32_bf16(ahi[ks], bhi, acc, 0, 0, 0);
            acc = __builtin_amdgcn_mfma_f32_16x16x32_bf16(alo[ks], bhi, acc, 0, 0, 0);
            acc = __builtin_amdgcn_mfma_f32_16x16x32_bf16(ahi[ks], blo, acc, 0, 0, 0);
        }
        const float asv = a[ct * 16 + lr];
        const float adv = a[OUT_DIM + ct * 16 + lr];
#pragma unroll
        for (int r = 0; r < 4; ++r) {
            int n = n0w + lk * 4 + r;
            if (n < N)
                z[(size_t)n * OUT_DIM + ct * 16 + lr] = __float2bfloat16(acc[r]);
            ps[r] += acc[r] * asv;
            pd[r] += acc[r] * adv;
        }
    }
    // reduce ps/pd over the 16 lanes sharing lk (xor of low 4 bits)
#pragma unroll
    for (int r = 0; r < 4; ++r) {
#pragma unroll
        for (int off = 1; off <= 8; off <<= 1) {
            ps[r] += __shfl_xor(ps[r], off);
            pd[r] += __shfl_xor(pd[r], off);
        }
        int n = n0w + lk * 4 + r;
        if (lr == 0 && n < N) {
            s_src[n] = ps[r];
            s_dst[n] = pd[r];
        }
    }
}

// ---------------------------------------------------------------------------
// Direct slotted scatter — byte-identical to the 285 us baseline (82 us).
// R3 post-mortem: MLP-batching the 8 iterations REGRESSED to 94 us (burst
// same-line atomic contention + predication VALU); keep the simple form.
// nt loads on src/dst: each line read once per XCD, keeps the streaming
// reads from evicting partially-filled ssort lines.
// ---------------------------------------------------------------------------
__global__ __launch_bounds__(256) void k_scatter(
    const int* __restrict__ src, const int* __restrict__ dst,
    int* __restrict__ cursor, int* __restrict__ ssort,
    int* __restrict__ ovfcnt, int2* __restrict__ ovf, int E)
{
    const int x = blockIdx.x & 7;
    const int c = blockIdx.x >> 3;
    const int e0 = c * CHUNK;
#pragma unroll
    for (int i = 0; i < CHUNK / 256; ++i) {
        int e = e0 + i * 256 + threadIdx.x;
        if (e < E) {
            int d = __builtin_nontemporal_load(&dst[e]);
            if (OWNER(d) == x) {
                int s = __builtin_nontemporal_load(&src[e]);
                int pos = atomicAdd(&cursor[d], 1);
                if (pos < CAP) {
                    ssort[d * CAP + pos] = s;
                } else {
                    int op = atomicAdd(ovfcnt, 1);
                    if (op < OVF_CAP) ovf[op] = make_int2(s, d);
                }
            }
        }
    }
}

// ---------------------------------------------------------------------------
// Fused per-node softmax + weighted gather + ELU. One wave/node, lane=col.
// Unshifted exp (validated R9/R10). 8-wide predicated gather unroll.
// nt on single-use streams (ssort read, out write) to keep z in L2.
// ---------------------------------------------------------------------------
__global__ __launch_bounds__(256) void k_node(
    const int* __restrict__ cursor, const int* __restrict__ ssort,
    const float* __restrict__ s_src, const float* __restrict__ s_dst,
    const int* __restrict__ ovfcnt, const int2* __restrict__ ovf,
    const __hip_bfloat16* __restrict__ z, float* __restrict__ out, int N)
{
    const int lane = threadIdx.x & 63;
    const int wave = threadIdx.x >> 6;
    const int n = blockIdx.x * 4 + wave;
    if (n >= N) return;

    const int deg_raw = cursor[n];
    if (deg_raw == 0) {                   // empty segment -> elu(0) = 0
        __builtin_nontemporal_store(0.f, &out[(size_t)n * OUT_DIM + lane]);
        return;
    }
    const int deg = min(deg_raw, CAP);
    const int base = n * CAP;
    const float sdn = s_dst[n];

    float sum = 0.f;                      // lane-partial softmax denom
    float acc = 0.f;                      // weighted feature accumulator
    {
        int kk = lane;                    // deg <= CAP=32 < 64: single pass
        int sv = 0;
        float ev = 0.f;
        if (kk < deg) {
            sv = __builtin_nontemporal_load(&ssort[base + kk]);
            float sc = s_src[sv] + sdn;
            sc = sc > 0.f ? sc : 0.01f * sc;   // leaky_relu
            ev = __expf(sc);
        }
        sum += ev;
        for (int j = 0; j < deg; j += 8) {
            float wgt[8], zv[8];
#pragma unroll
            for (int u = 0; u < 8; ++u) {
                int jj = j + u;
                bool ok = jj < deg;
                int s = __shfl(sv, ok ? jj : 0);
                float w = __shfl(ev, ok ? jj : 0);
                wgt[u] = ok ? w : 0.f;
                int sa = ok ? s : 0;
                zv[u] = __bfloat162float(z[(size_t)sa * OUT_DIM + lane]);
            }
#pragma unroll
            for (int u = 0; u < 8; ++u) acc += wgt[u] * zv[u];
        }
    }

    // exact overflow path (deg_raw > CAP): ~20 nodes, ovf list tiny
    if (deg_raw > CAP) {
        int oc = min(*ovfcnt, OVF_CAP);
        for (int i = 0; i < oc; ++i) {
            int2 p = ovf[i];
            if (p.y == n) {
                float sc = s_src[p.x] + sdn;
                sc = sc > 0.f ? sc : 0.01f * sc;
                float ev = __expf(sc);
                if (lane == 0) sum += ev;
                acc += ev * __bfloat162float(z[(size_t)p.x * OUT_DIM + lane]);
            }
        }
    }

#pragma unroll
    for (int off = 32; off >= 1; off >>= 1) sum += __shfl_xor(sum, off);

    float r = acc / sum;
    float o = r > 0.f ? r : expm1f(r);    // ELU, alpha=1
    __builtin_nontemporal_store(o, &out[(size_t)n * OUT_DIM + lane]);
}

// ---------------------------------------------------------------------------
extern "C" void kernel_launch(void* const* d_in, const int* in_sizes, int n_in,
                              void* d_out, int out_size, void* d_ws, size_t ws_size,
                              hipStream_t stream)
{
    (void)n_in; (void)out_size; (void)ws_size;

    const float* h  = (const float*)d_in[0];
    const int* src  = (const int*)d_in[1];
    const int* dst  = (const int*)d_in[2];
    const float* W  = (const float*)d_in[3];
    const float* a  = (const float*)d_in[4];
    const int N = in_sizes[0] / IN_DIM;
    const int E = in_sizes[1];
    float* out = (float*)d_out;

    char* wsp = (char*)d_ws;
    size_t off = 0;
    auto alloc = [&](size_t bytes) -> void* {
        void* p = wsp + off;
        off = (off + bytes + 255) & ~(size_t)255;
        return p;
    };
    __hip_bfloat16* z = (__hip_bfloat16*)alloc((size_t)N * OUT_DIM * 2);
    float* s_src = (float*)alloc((size_t)N * 4);
    float* s_dst = (float*)alloc((size_t)N * 4);
    int* cursor  = (int*)alloc((size_t)(N + 1) * 4);   // +1: ovfcnt tail
    int* ovfcnt  = cursor + N;
    int2* ovf    = (int2*)alloc((size_t)OVF_CAP * 8);
    int* ssort   = (int*)alloc((size_t)N * CAP * 4);   // 12.8 MB
    // total ~27 MB for N=1e5

    hipMemsetAsync(cursor, 0, (size_t)(N + 1) * 4, stream);

    const int nchunks = (E + CHUNK - 1) / CHUNK;
    k_gemm<<<(N + 63) / 64, 256, 0, stream>>>(h, W, a, z, s_src, s_dst, N);
    k_scatter<<<nchunks * 8, 256, 0, stream>>>(src, dst, cursor, ssort, ovfcnt, ovf, E);
    k_node<<<(N + 3) / 4, 256, 0, stream>>>(cursor, ssort, s_src, s_dst, ovfcnt, ovf, z, out, N);
}